// Round 11
// baseline (452.962 us; speedup 1.0000x reference)
//
#include <hip/hip_runtime.h>

#define N_NODES 50000
#define N_EDGES 800000
#define ETOT (N_EDGES + N_NODES)   // 850000
#define G_GRAPHS 256
#define F_IN 128
#define H1 12
#define D1 32
#define C1 (H1*D1)   // 384
#define C2 64
#define NEG 0.2f
#define SCAN_B 1024
#define NBLK_SCAN ((N_NODES + SCAN_B - 1)/SCAN_B)   // 49

using bf16x8  = __attribute__((ext_vector_type(8))) short;
using ushort8 = __attribute__((ext_vector_type(8))) unsigned short;
using f32x4   = __attribute__((ext_vector_type(4))) float;

__device__ __forceinline__ float lrelu(float x){ return x > 0.f ? x : NEG*x; }
__device__ __forceinline__ unsigned short f2bf(float f){
  unsigned u = __float_as_uint(f);
  u += 0x7fffu + ((u >> 16) & 1u);
  return (unsigned short)(u >> 16);
}
__device__ __forceinline__ float bf2f(unsigned short h){
  return __uint_as_float(((unsigned)h) << 16);
}
// exp without max-subtraction; clamp is overflow guard only (never hit, |l|<=~8 here)
__device__ __forceinline__ float wexp(float l){ return __expf(fminf(l, 30.f)); }

// ---------- merged prep: cast x, transpose W1/W2, build wAb ----------
#define B_CAST ((N_NODES*F_IN/4 + 255)/256)   // 6250
#define B_W1   ((F_IN*C1 + 255)/256)          // 192
#define B_W2   ((C1*C2 + 255)/256)            // 96
#define B_WAB  ((32*F_IN + 255)/256)          // 16
__global__ void prep_kernel(const float* __restrict__ x, const float* __restrict__ W1,
    const float* __restrict__ W2, const float* __restrict__ att_src,
    const float* __restrict__ att_dst, unsigned short* __restrict__ xb,
    unsigned short* __restrict__ w1t, unsigned short* __restrict__ w2t,
    unsigned short* __restrict__ wAb){
  int b = blockIdx.x, tid = threadIdx.x;
  if (b < B_CAST){
    int base = (b*256 + tid)*4;
    if (base >= N_NODES*F_IN) return;
    float4 v = *(const float4*)(x + base);
    ushort4 o; o.x=f2bf(v.x); o.y=f2bf(v.y); o.z=f2bf(v.z); o.w=f2bf(v.w);
    *(ushort4*)(xb + base) = o;
  } else if (b < B_CAST + B_W1){
    int i = (b - B_CAST)*256 + tid;
    if (i >= F_IN*C1) return;
    int n = i / F_IN, k = i % F_IN;
    w1t[i] = f2bf(W1[(size_t)k*C1 + n]);
  } else if (b < B_CAST + B_W1 + B_W2){
    int i = (b - B_CAST - B_W1)*256 + tid;
    if (i >= C1*C2) return;
    int n = i / C1, k = i % C1;
    w2t[i] = f2bf(W2[(size_t)k*C2 + n]);
  } else {
    int i = (b - B_CAST - B_W1 - B_W2)*256 + tid;
    if (i >= 32*F_IN) return;
    int c = i >> 7, k = i & 127;
    float v = 0.f;
    if (c < 12){
      #pragma unroll
      for (int dd=0; dd<D1; ++dd) v += W1[(size_t)k*C1 + c*D1 + dd] * att_src[c*D1 + dd];
    } else if (c < 24){
      int h = c - 12;
      #pragma unroll
      for (int dd=0; dd<D1; ++dd) v += W1[(size_t)k*C1 + h*D1 + dd] * att_dst[h*D1 + dd];
    }
    wAb[i] = f2bf(v);
  }
}

// ---------- bf16 MFMA GEMM (logits): C[M][N] = A[M][K] @ Bt[N][K]^T ----------
template<int BM,int BN,int WM,int WN,bool F32OUT>
__global__ __launch_bounds__(256) void gemm_mfma(const unsigned short* __restrict__ A,
    const unsigned short* __restrict__ Bt, void* __restrict__ Cv,
    int M, int N, int K){
  constexpr int BK = 32;
  __shared__ unsigned short As2[4][BM][8];
  __shared__ unsigned short Bs2[4][BN][8];
  const int tid  = threadIdx.x;
  const int wid  = tid >> 6, lane = tid & 63;
  constexpr int NWX = BN / WN;
  const int wrow = (wid / NWX) * WM, wcol = (wid % NWX) * WN;
  constexpr int MR = WM/16, NR = WN/16;
  const int row0 = blockIdx.x * BM, col0 = blockIdx.y * BN;
  const int r = lane & 15, koct = lane >> 4;
  f32x4 acc[MR][NR];
  #pragma unroll
  for (int m=0;m<MR;m++)
    #pragma unroll
    for (int n=0;n<NR;n++) acc[m][n] = f32x4{0.f,0.f,0.f,0.f};

  for (int k0 = 0; k0 < K; k0 += BK){
    for (int s = tid; s < BM*8; s += 256){
      int rr = s >> 3, cc = (s & 7) * 4;
      int gr = row0 + rr;
      ushort4 v = (gr < M) ? *(const ushort4*)(A + (size_t)gr*K + k0 + cc)
                           : ushort4{0,0,0,0};
      *(ushort4*)(&As2[cc>>3][rr][cc&7]) = v;
    }
    for (int s = tid; s < BN*8; s += 256){
      int rr = s >> 3, cc = (s & 7) * 4;
      ushort4 v = *(const ushort4*)(Bt + (size_t)(col0+rr)*K + k0 + cc);
      *(ushort4*)(&Bs2[cc>>3][rr][cc&7]) = v;
    }
    __syncthreads();
    bf16x8 af[MR], bq[NR];
    #pragma unroll
    for (int m=0;m<MR;m++) af[m] = *(const bf16x8*)(&As2[koct][wrow + m*16 + r][0]);
    #pragma unroll
    for (int n=0;n<NR;n++) bq[n] = *(const bf16x8*)(&Bs2[koct][wcol + n*16 + r][0]);
    #pragma unroll
    for (int m=0;m<MR;m++)
      #pragma unroll
      for (int n=0;n<NR;n++)
        acc[m][n] = __builtin_amdgcn_mfma_f32_16x16x32_bf16(af[m], bq[n], acc[m][n], 0,0,0);
    __syncthreads();
  }
  #pragma unroll
  for (int m=0;m<MR;m++){
    #pragma unroll
    for (int rr=0; rr<4; rr++){
      int grow = row0 + wrow + m*16 + koct*4 + rr;
      if (grow < M){
        #pragma unroll
        for (int n=0;n<NR;n++){
          if constexpr (F32OUT)
            ((float*)Cv)[(size_t)grow*N + col0 + wcol + n*16 + r] = acc[m][n][rr];
          else
            ((unsigned short*)Cv)[(size_t)grow*N + col0 + wcol + n*16 + r] = f2bf(acc[m][n][rr]);
        }
      }
    }
  }
}

// ---------- CSR build ----------
#define EGRID ((ETOT + 255)/256)          // 3321
#define NGRID ((N_NODES + 255)/256)       // 196
__global__ void count_cnt_kernel(const int* __restrict__ ei, const int* __restrict__ batch,
                                 int* __restrict__ counts, int* __restrict__ cnt){
  if ((int)blockIdx.x < EGRID){
    int e = blockIdx.x*256 + threadIdx.x;
    if (e >= ETOT) return;
    int d = (e < N_EDGES) ? ei[N_EDGES + e] : (e - N_EDGES);
    atomicAdd(&counts[d], 1);
  } else {
    int n = (blockIdx.x - EGRID)*256 + threadIdx.x;
    if (n < N_NODES) atomicAdd(&cnt[batch[n]], 1);
  }
}
__global__ __launch_bounds__(SCAN_B) void scan_pass1(const int* __restrict__ counts,
    int* __restrict__ excl, int* __restrict__ bsum){
  __shared__ int sdata[SCAN_B];
  int i = blockIdx.x*SCAN_B + threadIdx.x;
  int v = (i < N_NODES) ? counts[i] : 0;
  sdata[threadIdx.x] = v;
  __syncthreads();
  for (int off=1; off<SCAN_B; off<<=1){
    int t = (threadIdx.x >= off) ? sdata[threadIdx.x-off] : 0;
    __syncthreads();
    sdata[threadIdx.x] += t;
    __syncthreads();
  }
  if (i < N_NODES) excl[i] = sdata[threadIdx.x] - v;
  if (threadIdx.x == SCAN_B-1) bsum[blockIdx.x] = sdata[SCAN_B-1];
}
__global__ void scan_pass3(int* __restrict__ rowptr, const int* __restrict__ bsum,
                           int* __restrict__ cursor){
  __shared__ int carry_s;
  int sblk = blockIdx.x >> 2;
  if (threadIdx.x == 0){
    int c = 0;
    for (int b=0; b<sblk; ++b) c += bsum[b];
    carry_s = c;
  }
  __syncthreads();
  int i = blockIdx.x*256 + (int)threadIdx.x;
  if (i < N_NODES){
    int r = rowptr[i] + carry_s;
    rowptr[i] = r; cursor[i] = r;
  }
  if (i == N_NODES) rowptr[N_NODES] = ETOT;
}
__global__ void scatter_kernel(const int* __restrict__ ei, int* __restrict__ cursor,
                               int* __restrict__ csr_src){
  int e = blockIdx.x*blockDim.x + threadIdx.x;
  if (e >= ETOT) return;
  int s, d;
  if (e < N_EDGES){ s = ei[e]; d = ei[N_EDGES + e]; } else { s = d = e - N_EDGES; }
  int slot = atomicAdd(&cursor[d], 1);
  csr_src[slot] = s;
}

// ---------- conv1 MFMA-aggregation grand fusion ----------
// 1024 thr = 16 waves = 16 dst/block, ONE WAVE PER DST.
// Per 32-edge chunk: stage w (bf16) -> wlds[16hd][32e]; stage X^T -> Xt[128f][32e]
// (chunk-XOR-swizzled); 8x mfma_16x16x32 accumulate agg^T[feat][head] (32 VGPR).
// Epilogue (16 valid dst rows): W1-MFMA + bias + ReLU -> reluLDS; gemm2 (waves 0-3,
// K=384) -> h2 + a2 dots. out1 never materialized.
__global__ __launch_bounds__(1024) void agg1m_kernel(const int* __restrict__ rowptr,
    const int* __restrict__ csr, const unsigned short* __restrict__ xb,
    const float* __restrict__ asd, const unsigned short* __restrict__ w1t,
    const unsigned short* __restrict__ w2t, const float* __restrict__ bias1,
    const float* __restrict__ att_src2, const float* __restrict__ att_dst2,
    unsigned short* __restrict__ h2, float* __restrict__ asrc2, float* __restrict__ adst2){
  __shared__ unsigned short XtU[16*128*32];   // 131072 B ; aliased as aggU after loop
  __shared__ unsigned short wldsU[16*16*32];  // 16384 B  ; aliased as reluU + red
  unsigned short* aggU  = XtU;                // [16 slots][12*136 + 8] = 1640 elem/slot
  unsigned short* reluU = wldsU;              // [16 rows][392]
  float* redF = (float*)&wldsU[7168];         // 128 floats, above reluU's 6263 max idx

  const int tid  = threadIdx.x;
  const int wv   = tid >> 6;                  // 0..15 : dst slot = wave
  const int lane = tid & 63;
  const int e32  = lane & 31, half = lane >> 5;
  const int r    = lane & 15, koct = lane >> 4;   // MFMA frag coords
  const int d    = blockIdx.x*16 + wv;
  const int r0 = rowptr[d], r1 = rowptr[d+1];
  const int wvX = wv * (128*32);
  const int wvW = wv * (16*32);

  // zero wlds rows 12..15 once (B pad cols -> avoid NaN/denorm surprises)
  if (lane < 32){
    #pragma unroll
    for (int h=12; h<16; ++h) wldsU[wvW + h*32 + lane] = 0;
  }

  float4 ad0 = *(const float4*)(asd + (size_t)d*32 + 12);
  float4 ad1 = *(const float4*)(asd + (size_t)d*32 + 16);
  float4 ad2 = *(const float4*)(asd + (size_t)d*32 + 20);
  float ad[12] = {ad0.x,ad0.y,ad0.z,ad0.w, ad1.x,ad1.y,ad1.z,ad1.w, ad2.x,ad2.y,ad2.z,ad2.w};

  f32x4 c[8];
  #pragma unroll
  for (int t=0;t<8;t++) c[t] = f32x4{0.f,0.f,0.f,0.f};
  float ss[12];
  #pragma unroll
  for (int h=0;h<12;h++) ss[h] = 0.f;

  for (int c0 = r0; c0 < r1; c0 += 32){
    int nc = min(32, r1 - c0);
    int s_st = 0;
    if (lane < 32){
      if (lane < nc){
        s_st = csr[c0 + lane];
        float4 s0 = *(const float4*)(asd + (size_t)s_st*32);
        float4 s1 = *(const float4*)(asd + (size_t)s_st*32 + 4);
        float4 s2 = *(const float4*)(asd + (size_t)s_st*32 + 8);
        float as[12] = {s0.x,s0.y,s0.z,s0.w, s1.x,s1.y,s1.z,s1.w, s2.x,s2.y,s2.z,s2.w};
        #pragma unroll
        for (int h=0;h<12;h++){
          unsigned short wb = f2bf(wexp(lrelu(as[h] + ad[h])));
          wldsU[wvW + h*32 + lane] = wb;
          ss[h] += bf2f(wb);
        }
      } else {
        #pragma unroll
        for (int h=0;h<12;h++) wldsU[wvW + h*32 + lane] = 0;
      }
    }
    __builtin_amdgcn_wave_barrier();
    asm volatile("" ::: "memory");
    // Xt staging: lane covers (edge e32, feat half): 8 independent 16B loads
    int s = __shfl(s_st, e32);
    ushort8 xv0,xv1,xv2,xv3,xv4,xv5,xv6,xv7;
    if (e32 < nc){
      const unsigned short* xp = xb + (size_t)s*F_IN + half*64;
      xv0 = *(const ushort8*)(xp);      xv1 = *(const ushort8*)(xp+8);
      xv2 = *(const ushort8*)(xp+16);   xv3 = *(const ushort8*)(xp+24);
      xv4 = *(const ushort8*)(xp+32);   xv5 = *(const ushort8*)(xp+40);
      xv6 = *(const ushort8*)(xp+48);   xv7 = *(const ushort8*)(xp+56);
    } else {
      xv0=xv1=xv2=xv3=xv4=xv5=xv6=xv7 = ushort8{0,0,0,0,0,0,0,0};
    }
    {
      int ebase = wvX + (e32 & 7);
      int echunk = e32 >> 3;
      #pragma unroll
      for (int i=0;i<8;i++){
        ushort8 xv = (i==0)?xv0:(i==1)?xv1:(i==2)?xv2:(i==3)?xv3:(i==4)?xv4:(i==5)?xv5:(i==6)?xv6:xv7;
        #pragma unroll
        for (int j=0;j<8;j++){
          int f = half*64 + i*8 + j;
          XtU[ebase + f*32 + (((echunk + f)&3)<<3)] = (unsigned short)xv[j];
        }
      }
    }
    asm volatile("" ::: "memory");
    __builtin_amdgcn_wave_barrier();
    // MFMA: agg^T[feat][head] += Xt-tile @ wlds
    bf16x8 bq = *(const bf16x8*)&wldsU[wvW + r*32 + koct*8];
    #pragma unroll
    for (int t=0;t<8;t++){
      int feat = t*16 + r;
      bf16x8 af = *(const bf16x8*)&XtU[wvX + feat*32 + (((koct + feat)&3)<<3)];
      c[t] = __builtin_amdgcn_mfma_f32_16x16x32_bf16(af, bq, c[t], 0,0,0);
    }
    asm volatile("" ::: "memory");
    __builtin_amdgcn_wave_barrier();
  }

  // ss reduce over wave (staging lanes hold partials; others zero)
  #pragma unroll
  for (int h=0;h<12;h++){
    #pragma unroll
    for (int off=32; off; off>>=1) ss[h] += __shfl_xor(ss[h], off);
  }
  // per-lane inv for col r (compile-time-indexed select)
  float invr = 0.f;
  #pragma unroll
  for (int h=0;h<12;h++){ float iv = 1.f/ss[h]; invr = (r==h) ? iv : invr; }

  __syncthreads();   // ALL waves done with Xt before aggU overwrites (alias!)

  // write normalized agg rows: lane (r=head<12, koct) holds feats t*16+koct*4+rr
  if (r < 12){
    #pragma unroll
    for (int t=0;t<8;t++){
      #pragma unroll
      for (int rr=0;rr<4;rr++){
        int feat = t*16 + koct*4 + rr;
        aggU[wv*1640 + r*136 + feat] = f2bf(c[t][rr] * invr);
      }
    }
  }
  __syncthreads();

  // ---- W1 transform: 24 tiles (12 heads x 2 col-halves) over 16 waves ----
  for (int tt = wv; tt < 24; tt += 16){
    int h = tt >> 1, nb = tt & 1;
    f32x4 cw = {0.f,0.f,0.f,0.f};
    #pragma unroll
    for (int kk=0; kk<4; ++kk){
      bf16x8 af = *(const bf16x8*)&aggU[r*1640 + h*136 + kk*32 + koct*8];
      bf16x8 bq = *(const bf16x8*)(w1t + (size_t)(h*32 + nb*16 + r)*F_IN + kk*32 + koct*8);
      cw = __builtin_amdgcn_mfma_f32_16x16x32_bf16(af, bq, cw, 0,0,0);
    }
    int col = h*32 + nb*16 + r;
    float bv = bias1[col];
    #pragma unroll
    for (int rr=0; rr<4; ++rr){
      int row = koct*4 + rr;
      reluU[row*392 + col] = f2bf(fmaxf(cw[rr] + bv, 0.f));
    }
  }
  __syncthreads();

  // ---- gemm2 (waves 0..3): h2[16 dst][64] = relu_out1 @ W2, K=384 ----
  if (wv < 4){
    f32x4 h2acc = {0.f,0.f,0.f,0.f};
    #pragma unroll
    for (int kk=0; kk<12; ++kk){
      bf16x8 af = *(const bf16x8*)&reluU[r*392 + kk*32 + koct*8];
      bf16x8 bq = *(const bf16x8*)(w2t + (size_t)(wv*16 + r)*C1 + kk*32 + koct*8);
      h2acc = __builtin_amdgcn_mfma_f32_16x16x32_bf16(af, bq, h2acc, 0,0,0);
    }
    float attS = att_src2[wv*16 + r];
    float attD = att_dst2[wv*16 + r];
    float psum[4], pdum[4];
    #pragma unroll
    for (int rr=0; rr<4; ++rr){
      int row = koct*4 + rr;
      int gn = blockIdx.x*16 + row;
      h2[(size_t)gn*C2 + wv*16 + r] = f2bf(h2acc[rr]);
      psum[rr] = h2acc[rr]*attS;
      pdum[rr] = h2acc[rr]*attD;
    }
    #pragma unroll
    for (int rr=0; rr<4; ++rr){
      #pragma unroll
      for (int off=8; off; off>>=1){
        psum[rr] += __shfl_xor(psum[rr], off);
        pdum[rr] += __shfl_xor(pdum[rr], off);
      }
    }
    if (r == 0){
      #pragma unroll
      for (int rr=0; rr<4; ++rr){
        int row = koct*4 + rr;
        redF[(wv*16 + row)*2 + 0] = psum[rr];
        redF[(wv*16 + row)*2 + 1] = pdum[rr];
      }
    }
  }
  __syncthreads();
  if (tid < 32){
    int row = tid >> 1, which = tid & 1;
    float v = redF[row*2+which] + redF[(16+row)*2+which]
            + redF[(32+row)*2+which] + redF[(48+row)*2+which];
    int gn = blockIdx.x*16 + row;
    if (which == 0) asrc2[gn] = v; else adst2[gn] = v;
  }
}

// ---------- conv2: no-max softmax + aggregation + pool atomics ----------
__global__ __launch_bounds__(256) void agg2s_kernel(const int* __restrict__ rowptr,
    const int* __restrict__ csr, const unsigned short* __restrict__ h2,
    const float* __restrict__ asrc, const float* __restrict__ adst,
    const float* __restrict__ bias, const int* __restrict__ batch,
    float* __restrict__ pool){
  const int tid  = threadIdx.x;
  const int slot = tid >> 4;
  const int t16  = tid & 15;
  const int base = ((tid & 63) >> 4) * 16;
  const int d    = blockIdx.x*16 + slot;
  const int r0 = rowptr[d], r1 = rowptr[d+1];
  const float ad = adst[d];

  float ssp = 0.f;
  float a0=0.f, a1=0.f, a2=0.f, a3=0.f;

  for (int c0 = r0; c0 < r1; c0 += 16){
    int nc = min(16, r1 - c0);
    int s_st = 0; float w_st = 0.f;
    if (t16 < nc){
      s_st = csr[c0 + t16];
      w_st = wexp(lrelu(asrc[s_st] + ad));
      ssp += w_st;
    }
    int sA = __shfl(s_st, base + 0);
    ushort4 xA = *(const ushort4*)(h2 + (size_t)sA*C2 + t16*4);
    ushort4 xB = {0,0,0,0};
    if (nc > 1){
      int sB = __shfl(s_st, base + 1);
      xB = *(const ushort4*)(h2 + (size_t)sB*C2 + t16*4);
    }
    for (int e = 0; e < nc; ++e){
      ushort4 cx = xA;
      xA = xB;
      if (e + 2 < nc){
        int sN = __shfl(s_st, base + e + 2);
        xB = *(const ushort4*)(h2 + (size_t)sN*C2 + t16*4);
      }
      float w = __shfl(w_st, base + e);
      a0 += w*bf2f(cx.x);
      a1 += w*bf2f(cx.y);
      a2 += w*bf2f(cx.z);
      a3 += w*bf2f(cx.w);
    }
  }
  #pragma unroll
  for (int off=8; off; off>>=1) ssp += __shfl_xor(ssp, off);
  float inv = 1.f / ssp;
  int g = batch[d];
  int fb = t16*4;
  atomicAdd(&pool[g*C2 + fb+0], a0*inv + bias[fb+0]);
  atomicAdd(&pool[g*C2 + fb+1], a1*inv + bias[fb+1]);
  atomicAdd(&pool[g*C2 + fb+2], a2*inv + bias[fb+2]);
  atomicAdd(&pool[g*C2 + fb+3], a3*inv + bias[fb+3]);
}

__global__ void finalize_kernel(const float* __restrict__ sums, const int* __restrict__ cnt,
                                float* __restrict__ out){
  int i = blockIdx.x*blockDim.x + threadIdx.x;
  if (i >= G_GRAPHS*C2) return;
  int g = i >> 6;
  out[i] = sums[i] / fmaxf((float)cnt[g], 1.f);
}

// ---------- launch ----------
extern "C" void kernel_launch(void* const* d_in, const int* in_sizes, int n_in,
                              void* d_out, int out_size, void* d_ws, size_t ws_size,
                              hipStream_t stream) {
  const float* x        = (const float*)d_in[0];
  const int*   ei       = (const int*)  d_in[1];
  const int*   batch    = (const int*)  d_in[2];
  const float* W1       = (const float*)d_in[3];
  const float* att_src1 = (const float*)d_in[4];
  const float* att_dst1 = (const float*)d_in[5];
  const float* bias1    = (const float*)d_in[6];
  const float* W2       = (const float*)d_in[7];
  const float* att_src2 = (const float*)d_in[8];
  const float* att_dst2 = (const float*)d_in[9];
  const float* bias2    = (const float*)d_in[10];
  float* out = (float*)d_out;

  char* ws = (char*)d_ws;
  size_t o = 0;
  auto alloc = [&](size_t bytes)->size_t{ size_t r=o; o=(o+bytes+255)&~(size_t)255; return r; };

  size_t xb_o     = alloc((size_t)N_NODES*F_IN*2);   // 12.8 MB
  size_t w1t_o    = alloc((size_t)C1*F_IN*2);
  size_t w2t_o    = alloc((size_t)C2*C1*2);
  size_t wab_o    = alloc((size_t)32*F_IN*2);
  size_t asd_o    = alloc((size_t)N_NODES*32*4);     // 6.4 MB (src:0-11, dst:12-23)
  size_t h2_o     = alloc((size_t)N_NODES*C2*2);     // 6.4 MB
  size_t asrc2_o  = alloc((size_t)N_NODES*4);
  size_t adst2_o  = alloc((size_t)N_NODES*4);
  size_t zero_beg = o;
  size_t counts_o = alloc((size_t)N_NODES*4);
  size_t pool_o   = alloc((size_t)G_GRAPHS*C2*4);
  size_t cnt_o    = alloc((size_t)G_GRAPHS*4);
  size_t zero_end = o;
  size_t rowptr_o = alloc((size_t)(N_NODES+1)*4);
  size_t bsum_o   = alloc((size_t)NBLK_SCAN*4);
  size_t cursor_o = alloc((size_t)N_NODES*4);
  size_t csr_o    = alloc((size_t)ETOT*4);

  unsigned short* xb    = (unsigned short*)(ws + xb_o);
  unsigned short* w1t   = (unsigned short*)(ws + w1t_o);
  unsigned short* w2t   = (unsigned short*)(ws + w2t_o);
  unsigned short* wab   = (unsigned short*)(ws + wab_o);
  float* asd    = (float*)(ws + asd_o);
  unsigned short* h2b   = (unsigned short*)(ws + h2_o);
  float* asrc2  = (float*)(ws + asrc2_o);
  float* adst2  = (float*)(ws + adst2_o);
  int*   counts = (int*)  (ws + counts_o);
  float* poolf  = (float*)(ws + pool_o);
  int*   cnt    = (int*)  (ws + cnt_o);
  int*   rowptr = (int*)  (ws + rowptr_o);
  int*   bsum   = (int*)  (ws + bsum_o);
  int*   cursor = (int*)  (ws + cursor_o);
  int*   csrsrc = (int*)  (ws + csr_o);

  hipMemsetAsync(ws + zero_beg, 0, zero_end - zero_beg, stream);

  const int TPB = 256;

  // prep
  prep_kernel<<<B_CAST + B_W1 + B_W2 + B_WAB, TPB, 0, stream>>>(
      x, W1, W2, att_src1, att_dst1, xb, w1t, w2t, wab);

  // CSR build
  count_cnt_kernel<<<EGRID + NGRID, TPB, 0, stream>>>(ei, batch, counts, cnt);
  scan_pass1<<<NBLK_SCAN, SCAN_B, 0, stream>>>(counts, rowptr, bsum);
  scan_pass3<<<(N_NODES + 1 + 255)/256, TPB, 0, stream>>>(rowptr, bsum, cursor);
  scatter_kernel<<<EGRID, TPB, 0, stream>>>(ei, cursor, csrsrc);

  // conv1 logits
  gemm_mfma<64,32,32,16,true><<<dim3((N_NODES+63)/64, 1), 256, 0, stream>>>(xb, wab, asd, N_NODES, 32, F_IN);
  // conv1 MFMA-agg + W1 + gemm2 + a2 grand fusion
  agg1m_kernel<<<N_NODES/16, 1024, 0, stream>>>(rowptr, csrsrc, xb, asd, w1t, w2t,
                                                bias1, att_src2, att_dst2, h2b, asrc2, adst2);
  // conv2 aggregation + pool
  agg2s_kernel<<<(N_NODES+15)/16, TPB, 0, stream>>>(rowptr, csrsrc, h2b, asrc2, adst2, bias2, batch, poolf);

  // pool finalize
  finalize_kernel<<<(G_GRAPHS*C2 + TPB-1)/TPB, TPB, 0, stream>>>(poolf, cnt, out);
}

// Round 12
// 418.685 us; speedup vs baseline: 1.0819x; 1.0819x over previous
//
#include <hip/hip_runtime.h>

#define N_NODES 50000
#define N_EDGES 800000
#define ETOT (N_EDGES + N_NODES)   // 850000
#define G_GRAPHS 256
#define F_IN 128
#define H1 12
#define D1 32
#define C1 (H1*D1)   // 384
#define C2 64
#define NEG 0.2f
#define SCAN_B 1024
#define NBLK_SCAN ((N_NODES + SCAN_B - 1)/SCAN_B)   // 49

using bf16x8  = __attribute__((ext_vector_type(8))) short;
using ushort8 = __attribute__((ext_vector_type(8))) unsigned short;
using f32x4   = __attribute__((ext_vector_type(4))) float;

__device__ __forceinline__ float lrelu(float x){ return x > 0.f ? x : NEG*x; }
__device__ __forceinline__ unsigned short f2bf(float f){
  unsigned u = __float_as_uint(f);
  u += 0x7fffu + ((u >> 16) & 1u);
  return (unsigned short)(u >> 16);
}
__device__ __forceinline__ float bf2f(unsigned short h){
  return __uint_as_float(((unsigned)h) << 16);
}
// exp without max-subtraction; clamp is overflow guard only (never hit, |l|<=~8 here)
__device__ __forceinline__ float wexp(float l){ return __expf(fminf(l, 30.f)); }

// ---------- merged prep: cast x, transpose W1/W2, build wAb ----------
#define B_CAST ((N_NODES*F_IN/4 + 255)/256)   // 6250
#define B_W1   ((F_IN*C1 + 255)/256)          // 192
#define B_W2   ((C1*C2 + 255)/256)            // 96
#define B_WAB  ((32*F_IN + 255)/256)          // 16
__global__ void prep_kernel(const float* __restrict__ x, const float* __restrict__ W1,
    const float* __restrict__ W2, const float* __restrict__ att_src,
    const float* __restrict__ att_dst, unsigned short* __restrict__ xb,
    unsigned short* __restrict__ w1t, unsigned short* __restrict__ w2t,
    unsigned short* __restrict__ wAb){
  int b = blockIdx.x, tid = threadIdx.x;
  if (b < B_CAST){
    int base = (b*256 + tid)*4;
    if (base >= N_NODES*F_IN) return;
    float4 v = *(const float4*)(x + base);
    ushort4 o; o.x=f2bf(v.x); o.y=f2bf(v.y); o.z=f2bf(v.z); o.w=f2bf(v.w);
    *(ushort4*)(xb + base) = o;
  } else if (b < B_CAST + B_W1){
    int i = (b - B_CAST)*256 + tid;
    if (i >= F_IN*C1) return;
    int n = i / F_IN, k = i % F_IN;
    w1t[i] = f2bf(W1[(size_t)k*C1 + n]);
  } else if (b < B_CAST + B_W1 + B_W2){
    int i = (b - B_CAST - B_W1)*256 + tid;
    if (i >= C1*C2) return;
    int n = i / C1, k = i % C1;
    w2t[i] = f2bf(W2[(size_t)k*C2 + n]);
  } else {
    int i = (b - B_CAST - B_W1 - B_W2)*256 + tid;
    if (i >= 32*F_IN) return;
    int c = i >> 7, k = i & 127;
    float v = 0.f;
    if (c < 12){
      #pragma unroll
      for (int dd=0; dd<D1; ++dd) v += W1[(size_t)k*C1 + c*D1 + dd] * att_src[c*D1 + dd];
    } else if (c < 24){
      int h = c - 12;
      #pragma unroll
      for (int dd=0; dd<D1; ++dd) v += W1[(size_t)k*C1 + h*D1 + dd] * att_dst[h*D1 + dd];
    }
    wAb[i] = f2bf(v);
  }
}

// ---------- bf16 MFMA GEMM (logits): C[M][N] = A[M][K] @ Bt[N][K]^T ----------
template<int BM,int BN,int WM,int WN,bool F32OUT>
__global__ __launch_bounds__(256) void gemm_mfma(const unsigned short* __restrict__ A,
    const unsigned short* __restrict__ Bt, void* __restrict__ Cv,
    int M, int N, int K){
  constexpr int BK = 32;
  __shared__ unsigned short As2[4][BM][8];
  __shared__ unsigned short Bs2[4][BN][8];
  const int tid  = threadIdx.x;
  const int wid  = tid >> 6, lane = tid & 63;
  constexpr int NWX = BN / WN;
  const int wrow = (wid / NWX) * WM, wcol = (wid % NWX) * WN;
  constexpr int MR = WM/16, NR = WN/16;
  const int row0 = blockIdx.x * BM, col0 = blockIdx.y * BN;
  const int r = lane & 15, koct = lane >> 4;
  f32x4 acc[MR][NR];
  #pragma unroll
  for (int m=0;m<MR;m++)
    #pragma unroll
    for (int n=0;n<NR;n++) acc[m][n] = f32x4{0.f,0.f,0.f,0.f};

  for (int k0 = 0; k0 < K; k0 += BK){
    for (int s = tid; s < BM*8; s += 256){
      int rr = s >> 3, cc = (s & 7) * 4;
      int gr = row0 + rr;
      ushort4 v = (gr < M) ? *(const ushort4*)(A + (size_t)gr*K + k0 + cc)
                           : ushort4{0,0,0,0};
      *(ushort4*)(&As2[cc>>3][rr][cc&7]) = v;
    }
    for (int s = tid; s < BN*8; s += 256){
      int rr = s >> 3, cc = (s & 7) * 4;
      ushort4 v = *(const ushort4*)(Bt + (size_t)(col0+rr)*K + k0 + cc);
      *(ushort4*)(&Bs2[cc>>3][rr][cc&7]) = v;
    }
    __syncthreads();
    bf16x8 af[MR], bq[NR];
    #pragma unroll
    for (int m=0;m<MR;m++) af[m] = *(const bf16x8*)(&As2[koct][wrow + m*16 + r][0]);
    #pragma unroll
    for (int n=0;n<NR;n++) bq[n] = *(const bf16x8*)(&Bs2[koct][wcol + n*16 + r][0]);
    #pragma unroll
    for (int m=0;m<MR;m++)
      #pragma unroll
      for (int n=0;n<NR;n++)
        acc[m][n] = __builtin_amdgcn_mfma_f32_16x16x32_bf16(af[m], bq[n], acc[m][n], 0,0,0);
    __syncthreads();
  }
  #pragma unroll
  for (int m=0;m<MR;m++){
    #pragma unroll
    for (int rr=0; rr<4; rr++){
      int grow = row0 + wrow + m*16 + koct*4 + rr;
      if (grow < M){
        #pragma unroll
        for (int n=0;n<NR;n++){
          if constexpr (F32OUT)
            ((float*)Cv)[(size_t)grow*N + col0 + wcol + n*16 + r] = acc[m][n][rr];
          else
            ((unsigned short*)Cv)[(size_t)grow*N + col0 + wcol + n*16 + r] = f2bf(acc[m][n][rr]);
        }
      }
    }
  }
}

// ---------- CSR build ----------
#define EGRID ((ETOT + 255)/256)          // 3321
#define NGRID ((N_NODES + 255)/256)       // 196
__global__ void count_cnt_kernel(const int* __restrict__ ei, const int* __restrict__ batch,
                                 int* __restrict__ counts, int* __restrict__ cnt){
  if ((int)blockIdx.x < EGRID){
    int e = blockIdx.x*256 + threadIdx.x;
    if (e >= ETOT) return;
    int d = (e < N_EDGES) ? ei[N_EDGES + e] : (e - N_EDGES);
    atomicAdd(&counts[d], 1);
  } else {
    int n = (blockIdx.x - EGRID)*256 + threadIdx.x;
    if (n < N_NODES) atomicAdd(&cnt[batch[n]], 1);
  }
}
__global__ __launch_bounds__(SCAN_B) void scan_pass1(const int* __restrict__ counts,
    int* __restrict__ excl, int* __restrict__ bsum){
  __shared__ int sdata[SCAN_B];
  int i = blockIdx.x*SCAN_B + threadIdx.x;
  int v = (i < N_NODES) ? counts[i] : 0;
  sdata[threadIdx.x] = v;
  __syncthreads();
  for (int off=1; off<SCAN_B; off<<=1){
    int t = (threadIdx.x >= off) ? sdata[threadIdx.x-off] : 0;
    __syncthreads();
    sdata[threadIdx.x] += t;
    __syncthreads();
  }
  if (i < N_NODES) excl[i] = sdata[threadIdx.x] - v;
  if (threadIdx.x == SCAN_B-1) bsum[blockIdx.x] = sdata[SCAN_B-1];
}
__global__ void scan_pass3(int* __restrict__ rowptr, const int* __restrict__ bsum,
                           int* __restrict__ cursor){
  __shared__ int carry_s;
  int sblk = blockIdx.x >> 2;
  if (threadIdx.x == 0){
    int c = 0;
    for (int b=0; b<sblk; ++b) c += bsum[b];
    carry_s = c;
  }
  __syncthreads();
  int i = blockIdx.x*256 + (int)threadIdx.x;
  if (i < N_NODES){
    int r = rowptr[i] + carry_s;
    rowptr[i] = r; cursor[i] = r;
  }
  if (i == N_NODES) rowptr[N_NODES] = ETOT;
}
__global__ void scatter_kernel(const int* __restrict__ ei, int* __restrict__ cursor,
                               int* __restrict__ csr_src, int* __restrict__ csr_dst){
  int e = blockIdx.x*blockDim.x + threadIdx.x;
  if (e >= ETOT) return;
  int s, d;
  if (e < N_EDGES){ s = ei[e]; d = ei[N_EDGES + e]; } else { s = d = e - N_EDGES; }
  int slot = atomicAdd(&cursor[d], 1);
  csr_src[slot] = s;
  csr_dst[slot] = d;
}

// ---------- edge-parallel weight precompute: walpha[j][12] = bf16(exp(lrelu(aS+aD))) ----------
__global__ void wprep_kernel(const int* __restrict__ csr, const int* __restrict__ csrd,
                             const float* __restrict__ asd, unsigned short* __restrict__ walpha){
  int j = blockIdx.x*256 + threadIdx.x;
  if (j >= ETOT) return;
  int s = csr[j], d = csrd[j];
  float4 s0 = *(const float4*)(asd + (size_t)s*32);
  float4 s1 = *(const float4*)(asd + (size_t)s*32 + 4);
  float4 s2 = *(const float4*)(asd + (size_t)s*32 + 8);
  float4 d0 = *(const float4*)(asd + (size_t)d*32 + 12);
  float4 d1 = *(const float4*)(asd + (size_t)d*32 + 16);
  float4 d2 = *(const float4*)(asd + (size_t)d*32 + 20);
  float as[12] = {s0.x,s0.y,s0.z,s0.w, s1.x,s1.y,s1.z,s1.w, s2.x,s2.y,s2.z,s2.w};
  float ad[12] = {d0.x,d0.y,d0.z,d0.w, d1.x,d1.y,d1.z,d1.w, d2.x,d2.y,d2.z,d2.w};
  unsigned short wb[12];
  #pragma unroll
  for (int h=0;h<12;h++) wb[h] = f2bf(wexp(lrelu(as[h] + ad[h])));
  unsigned short* wp = walpha + (size_t)j*12;
  *(ushort4*)(wp)   = ushort4{wb[0],wb[1],wb[2],wb[3]};
  *(ushort4*)(wp+4) = ushort4{wb[4],wb[5],wb[6],wb[7]};
  *(ushort4*)(wp+8) = ushort4{wb[8],wb[9],wb[10],wb[11]};
}

// ---------- conv1 grand-fused: precomputed-w softmax + x-space agg + W1 MFMA + ReLU
//            + gemm2 partials (h2 = relu_out1 @ W2) + a2 dots. out1 never materialized.
// 256 thr = 4 waves = 16 dst/block, 16 lanes/dst (R8-proven loop); 3-deep x prefetch.
__global__ __launch_bounds__(256) void agg1g_kernel(const int* __restrict__ rowptr,
    const int* __restrict__ csr, const unsigned short* __restrict__ xb,
    const unsigned short* __restrict__ walpha, const unsigned short* __restrict__ w1t,
    const unsigned short* __restrict__ w2t, const float* __restrict__ bias1,
    const float* __restrict__ att_src2, const float* __restrict__ att_dst2,
    unsigned short* __restrict__ h2, float* __restrict__ asrc2, float* __restrict__ adst2){
  constexpr int ROWE = 6*F_IN + 8;            // 776 ushorts, per-slot agg row (6 heads)
  constexpr int WROW = 16*12 + 4;             // 196 floats, per-slot weight row
  constexpr int ROWR = 192 + 8;               // 200 ushorts, relu-out1 half-row
  __shared__ unsigned short agg[16*ROWE];     // 24832 B
  __shared__ float wlds[16][WROW];            // 12544 B (reused as reluLDS + a2-red)

  unsigned short* reluLDS = (unsigned short*)&wlds[0][0];   // 16 x ROWR ushorts = 6400 B
  float* red = (float*)&agg[0];                              // a2 reduce scratch

  const int tid  = threadIdx.x;
  const int slot = tid >> 4;                  // 0..15 dst in block
  const int t16  = tid & 15;
  const int base = ((tid & 63) >> 4) * 16;    // 16-lane group base within wave
  const int d    = blockIdx.x*16 + slot;
  const int r0 = rowptr[d], r1 = rowptr[d+1];

  float acc[12][8];
  #pragma unroll
  for (int h=0;h<12;h++)
    #pragma unroll
    for (int i=0;i<8;i++) acc[h][i] = 0.f;
  float ss[12];
  #pragma unroll
  for (int h=0;h<12;h++) ss[h] = 0.f;

  // ---- main loop: 16-edge chunks; staging lane loads precomputed w (bf16, coalesced) ----
  for (int c0 = r0; c0 < r1; c0 += 16){
    int nc = min(16, r1 - c0);
    int s_st = 0;
    if (t16 < nc){
      int j = c0 + t16;
      s_st = csr[j];
      const unsigned short* wp = walpha + (size_t)j*12;
      ushort4 u0 = *(const ushort4*)(wp);
      ushort4 u1 = *(const ushort4*)(wp+4);
      ushort4 u2 = *(const ushort4*)(wp+8);
      float w[12] = {bf2f(u0.x),bf2f(u0.y),bf2f(u0.z),bf2f(u0.w),
                     bf2f(u1.x),bf2f(u1.y),bf2f(u1.z),bf2f(u1.w),
                     bf2f(u2.x),bf2f(u2.y),bf2f(u2.z),bf2f(u2.w)};
      #pragma unroll
      for (int h=0;h<12;h++) ss[h] += w[h];
      *(float4*)(&wlds[slot][t16*12 + 0]) = float4{w[0],w[1],w[2],w[3]};
      *(float4*)(&wlds[slot][t16*12 + 4]) = float4{w[4],w[5],w[6],w[7]};
      *(float4*)(&wlds[slot][t16*12 + 8]) = float4{w[8],w[9],w[10],w[11]};
    }
    __builtin_amdgcn_wave_barrier();
    // 3-deep x prefetch (s via shfl from staged regs)
    int sA = __shfl(s_st, base + 0);
    ushort8 xA = *(const ushort8*)(xb + (size_t)sA*F_IN + t16*8);
    ushort8 xB = {0,0,0,0,0,0,0,0}, xC = {0,0,0,0,0,0,0,0};
    if (nc > 1){
      int sB = __shfl(s_st, base + 1);
      xB = *(const ushort8*)(xb + (size_t)sB*F_IN + t16*8);
    }
    if (nc > 2){
      int sC = __shfl(s_st, base + 2);
      xC = *(const ushort8*)(xb + (size_t)sC*F_IN + t16*8);
    }
    for (int e = 0; e < nc; ++e){
      ushort8 cx = xA;
      xA = xB; xB = xC;
      if (e + 3 < nc){
        int sN = __shfl(s_st, base + e + 3);
        xC = *(const ushort8*)(xb + (size_t)sN*F_IN + t16*8);
      }
      float4 w0 = *(const float4*)(&wlds[slot][e*12 + 0]);
      float4 w1 = *(const float4*)(&wlds[slot][e*12 + 4]);
      float4 w2 = *(const float4*)(&wlds[slot][e*12 + 8]);
      float xf[8];
      #pragma unroll
      for (int i=0;i<8;i++) xf[i] = bf2f((unsigned short)cx[i]);
      float w[12] = {w0.x,w0.y,w0.z,w0.w, w1.x,w1.y,w1.z,w1.w, w2.x,w2.y,w2.z,w2.w};
      #pragma unroll
      for (int h=0;h<12;h++)
        #pragma unroll
        for (int i=0;i<8;i++) acc[h][i] += w[h]*xf[i];
    }
    __builtin_amdgcn_wave_barrier();
  }

  // reduce ss over 16-lane group; normalize factors
  #pragma unroll
  for (int h=0;h<12;h++){
    #pragma unroll
    for (int off=8; off; off>>=1) ss[h] += __shfl_xor(ss[h], off);
  }
  float inv[12];
  #pragma unroll
  for (int h=0;h<12;h++) inv[h] = 1.f / ss[h];

  // ---- epilogue: per 6-head half: agg->LDS, W1-MFMA + bias + ReLU -> reluLDS,
  //      then partial gemm2 (K=192) accumulating h2 in regs ----
  const int wv = tid >> 6, wl = tid & 63;
  const int er = wl & 15, eq = wl >> 4;
  f32x4 h2acc = {0.f,0.f,0.f,0.f};
  #pragma unroll
  for (int hf = 0; hf < 2; ++hf){
    __syncthreads();   // main loop done (hf=0) / prev half's reluLDS+agg reads done (hf=1)
    #pragma unroll
    for (int h = 0; h < 6; ++h){
      int hh = hf*6 + h;
      ushort8 v;
      #pragma unroll
      for (int i=0;i<8;i++) v[i] = f2bf(acc[hh][i]*inv[hh]);
      *(ushort8*)(&agg[slot*ROWE + h*F_IN + t16*8]) = v;
    }
    __syncthreads();
    // W1 transform: 12 tiles (192 cols) over 4 waves; bias+ReLU -> reluLDS
    for (int tt = wv; tt < 12; tt += 4){
      int h = tt >> 1, nb = tt & 1;
      int hh = hf*6 + h;
      f32x4 c = {0.f,0.f,0.f,0.f};
      #pragma unroll
      for (int kk=0; kk<4; ++kk){
        bf16x8 af = *(const bf16x8*)(&agg[er*ROWE + h*F_IN + kk*32 + eq*8]);
        bf16x8 bq = *(const bf16x8*)(w1t + (size_t)(hh*32 + nb*16 + er)*F_IN + kk*32 + eq*8);
        c = __builtin_amdgcn_mfma_f32_16x16x32_bf16(af, bq, c, 0,0,0);
      }
      int lcol = tt*16 + er;                    // local col within half (0..191)
      float bv = bias1[hf*192 + lcol];
      #pragma unroll
      for (int rr=0; rr<4; ++rr){
        int row = eq*4 + rr;                    // dst row 0..15
        reluLDS[row*ROWR + lcol] = f2bf(fmaxf(c[rr] + bv, 0.f));
      }
    }
    __syncthreads();
    // partial gemm2: wave wv owns h2 cols [wv*16, wv*16+16), K=192 this half
    #pragma unroll
    for (int kk=0; kk<6; ++kk){
      bf16x8 af = *(const bf16x8*)(&reluLDS[er*ROWR + kk*32 + eq*8]);
      bf16x8 bq = *(const bf16x8*)(w2t + (size_t)(wv*16 + er)*C1 + hf*192 + kk*32 + eq*8);
      h2acc = __builtin_amdgcn_mfma_f32_16x16x32_bf16(af, bq, h2acc, 0,0,0);
    }
  }
  __syncthreads();   // reluLDS/agg reads done; agg region reusable as red

  // ---- write h2 (bf16) + a2 dots ----
  float attS = att_src2[wv*16 + er];
  float attD = att_dst2[wv*16 + er];
  float psum[4], pdum[4];
  #pragma unroll
  for (int rr=0; rr<4; ++rr){
    int row = eq*4 + rr;
    int gn = blockIdx.x*16 + row;
    h2[(size_t)gn*C2 + wv*16 + er] = f2bf(h2acc[rr]);
    psum[rr] = h2acc[rr]*attS;
    pdum[rr] = h2acc[rr]*attD;
  }
  #pragma unroll
  for (int rr=0; rr<4; ++rr){
    #pragma unroll
    for (int off=8; off; off>>=1){
      psum[rr] += __shfl_xor(psum[rr], off);
      pdum[rr] += __shfl_xor(pdum[rr], off);
    }
  }
  if (er == 0){
    #pragma unroll
    for (int rr=0; rr<4; ++rr){
      int row = eq*4 + rr;
      red[(wv*16 + row)*2 + 0] = psum[rr];
      red[(wv*16 + row)*2 + 1] = pdum[rr];
    }
  }
  __syncthreads();
  if (tid < 32){
    int row = tid >> 1, which = tid & 1;
    float v = red[row*2+which] + red[(16+row)*2+which] + red[(32+row)*2+which] + red[(48+row)*2+which];
    int gn = blockIdx.x*16 + row;
    if (which == 0) asrc2[gn] = v; else adst2[gn] = v;
  }
}

// ---------- conv2: no-max softmax + aggregation + pool atomics ----------
__global__ __launch_bounds__(256) void agg2s_kernel(const int* __restrict__ rowptr,
    const int* __restrict__ csr, const unsigned short* __restrict__ h2,
    const float* __restrict__ asrc, const float* __restrict__ adst,
    const float* __restrict__ bias, const int* __restrict__ batch,
    float* __restrict__ pool){
  const int tid  = threadIdx.x;
  const int slot = tid >> 4;
  const int t16  = tid & 15;
  const int base = ((tid & 63) >> 4) * 16;
  const int d    = blockIdx.x*16 + slot;
  const int r0 = rowptr[d], r1 = rowptr[d+1];
  const float ad = adst[d];

  float ssp = 0.f;
  float a0=0.f, a1=0.f, a2=0.f, a3=0.f;

  for (int c0 = r0; c0 < r1; c0 += 16){
    int nc = min(16, r1 - c0);
    int s_st = 0; float w_st = 0.f;
    if (t16 < nc){
      s_st = csr[c0 + t16];
      w_st = wexp(lrelu(asrc[s_st] + ad));
      ssp += w_st;
    }
    int sA = __shfl(s_st, base + 0);
    ushort4 xA = *(const ushort4*)(h2 + (size_t)sA*C2 + t16*4);
    ushort4 xB = {0,0,0,0}, xC = {0,0,0,0};
    if (nc > 1){
      int sB = __shfl(s_st, base + 1);
      xB = *(const ushort4*)(h2 + (size_t)sB*C2 + t16*4);
    }
    if (nc > 2){
      int sC = __shfl(s_st, base + 2);
      xC = *(const ushort4*)(h2 + (size_t)sC*C2 + t16*4);
    }
    for (int e = 0; e < nc; ++e){
      ushort4 cx = xA;
      xA = xB; xB = xC;
      if (e + 3 < nc){
        int sN = __shfl(s_st, base + e + 3);
        xC = *(const ushort4*)(h2 + (size_t)sN*C2 + t16*4);
      }
      float w = __shfl(w_st, base + e);
      a0 += w*bf2f(cx.x);
      a1 += w*bf2f(cx.y);
      a2 += w*bf2f(cx.z);
      a3 += w*bf2f(cx.w);
    }
  }
  #pragma unroll
  for (int off=8; off; off>>=1) ssp += __shfl_xor(ssp, off);
  float inv = 1.f / ssp;
  int g = batch[d];
  int fb = t16*4;
  atomicAdd(&pool[g*C2 + fb+0], a0*inv + bias[fb+0]);
  atomicAdd(&pool[g*C2 + fb+1], a1*inv + bias[fb+1]);
  atomicAdd(&pool[g*C2 + fb+2], a2*inv + bias[fb+2]);
  atomicAdd(&pool[g*C2 + fb+3], a3*inv + bias[fb+3]);
}

__global__ void finalize_kernel(const float* __restrict__ sums, const int* __restrict__ cnt,
                                float* __restrict__ out){
  int i = blockIdx.x*blockDim.x + threadIdx.x;
  if (i >= G_GRAPHS*C2) return;
  int g = i >> 6;
  out[i] = sums[i] / fmaxf((float)cnt[g], 1.f);
}

// ---------- launch ----------
extern "C" void kernel_launch(void* const* d_in, const int* in_sizes, int n_in,
                              void* d_out, int out_size, void* d_ws, size_t ws_size,
                              hipStream_t stream) {
  const float* x        = (const float*)d_in[0];
  const int*   ei       = (const int*)  d_in[1];
  const int*   batch    = (const int*)  d_in[2];
  const float* W1       = (const float*)d_in[3];
  const float* att_src1 = (const float*)d_in[4];
  const float* att_dst1 = (const float*)d_in[5];
  const float* bias1    = (const float*)d_in[6];
  const float* W2       = (const float*)d_in[7];
  const float* att_src2 = (const float*)d_in[8];
  const float* att_dst2 = (const float*)d_in[9];
  const float* bias2    = (const float*)d_in[10];
  float* out = (float*)d_out;

  char* ws = (char*)d_ws;
  size_t o = 0;
  auto alloc = [&](size_t bytes)->size_t{ size_t r=o; o=(o+bytes+255)&~(size_t)255; return r; };

  size_t xb_o     = alloc((size_t)N_NODES*F_IN*2);   // 12.8 MB
  size_t w1t_o    = alloc((size_t)C1*F_IN*2);
  size_t w2t_o    = alloc((size_t)C2*C1*2);
  size_t wab_o    = alloc((size_t)32*F_IN*2);
  size_t asd_o    = alloc((size_t)N_NODES*32*4);     // 6.4 MB (src:0-11, dst:12-23)
  size_t h2_o     = alloc((size_t)N_NODES*C2*2);     // 6.4 MB
  size_t asrc2_o  = alloc((size_t)N_NODES*4);
  size_t adst2_o  = alloc((size_t)N_NODES*4);
  size_t walpha_o = alloc((size_t)ETOT*12*2);        // 20.4 MB bf16 unnormalized w
  size_t zero_beg = o;
  size_t counts_o = alloc((size_t)N_NODES*4);
  size_t pool_o   = alloc((size_t)G_GRAPHS*C2*4);
  size_t cnt_o    = alloc((size_t)G_GRAPHS*4);
  size_t zero_end = o;
  size_t rowptr_o = alloc((size_t)(N_NODES+1)*4);
  size_t bsum_o   = alloc((size_t)NBLK_SCAN*4);
  size_t cursor_o = alloc((size_t)N_NODES*4);
  size_t csr_o    = alloc((size_t)ETOT*4);
  size_t csrd_o   = alloc((size_t)ETOT*4);

  unsigned short* xb    = (unsigned short*)(ws + xb_o);
  unsigned short* w1t   = (unsigned short*)(ws + w1t_o);
  unsigned short* w2t   = (unsigned short*)(ws + w2t_o);
  unsigned short* wab   = (unsigned short*)(ws + wab_o);
  float* asd    = (float*)(ws + asd_o);
  unsigned short* h2b   = (unsigned short*)(ws + h2_o);
  float* asrc2  = (float*)(ws + asrc2_o);
  float* adst2  = (float*)(ws + adst2_o);
  unsigned short* walpha = (unsigned short*)(ws + walpha_o);
  int*   counts = (int*)  (ws + counts_o);
  float* poolf  = (float*)(ws + pool_o);
  int*   cnt    = (int*)  (ws + cnt_o);
  int*   rowptr = (int*)  (ws + rowptr_o);
  int*   bsum   = (int*)  (ws + bsum_o);
  int*   cursor = (int*)  (ws + cursor_o);
  int*   csrsrc = (int*)  (ws + csr_o);
  int*   csrdst = (int*)  (ws + csrd_o);

  hipMemsetAsync(ws + zero_beg, 0, zero_end - zero_beg, stream);

  const int TPB = 256;

  // prep
  prep_kernel<<<B_CAST + B_W1 + B_W2 + B_WAB, TPB, 0, stream>>>(
      x, W1, W2, att_src1, att_dst1, xb, w1t, w2t, wab);

  // CSR build
  count_cnt_kernel<<<EGRID + NGRID, TPB, 0, stream>>>(ei, batch, counts, cnt);
  scan_pass1<<<NBLK_SCAN, SCAN_B, 0, stream>>>(counts, rowptr, bsum);
  scan_pass3<<<(N_NODES + 1 + 255)/256, TPB, 0, stream>>>(rowptr, bsum, cursor);
  scatter_kernel<<<EGRID, TPB, 0, stream>>>(ei, cursor, csrsrc, csrdst);

  // conv1 logits
  gemm_mfma<64,32,32,16,true><<<dim3((N_NODES+63)/64, 1), 256, 0, stream>>>(xb, wab, asd, N_NODES, 32, F_IN);
  // per-edge weights (bf16, unnormalized, no-max)
  wprep_kernel<<<EGRID, TPB, 0, stream>>>(csrsrc, csrdst, asd, walpha);
  // conv1 agg + W1 + gemm2 + a2 grand fusion
  agg1g_kernel<<<N_NODES/16, TPB, 0, stream>>>(rowptr, csrsrc, xb, walpha, w1t, w2t,
                                               bias1, att_src2, att_dst2, h2b, asrc2, adst2);
  // conv2 aggregation + pool
  agg2s_kernel<<<(N_NODES+15)/16, TPB, 0, stream>>>(rowptr, csrsrc, h2b, asrc2, adst2, bias2, batch, poolf);

  // pool finalize
  finalize_kernel<<<(G_GRAPHS*C2 + TPB-1)/TPB, TPB, 0, stream>>>(poolf, cnt, out);
}

// Round 13
// 413.997 us; speedup vs baseline: 1.0941x; 1.0113x over previous
//
#include <hip/hip_runtime.h>

#define N_NODES 50000
#define N_EDGES 800000
#define ETOT (N_EDGES + N_NODES)   // 850000
#define G_GRAPHS 256
#define F_IN 128
#define H1 12
#define D1 32
#define C1 (H1*D1)   // 384
#define C2 64
#define NEG 0.2f
#define SCAN_B 1024
#define NBLK_SCAN ((N_NODES + SCAN_B - 1)/SCAN_B)   // 49

using bf16x8  = __attribute__((ext_vector_type(8))) short;
using ushort8 = __attribute__((ext_vector_type(8))) unsigned short;
using f32x4   = __attribute__((ext_vector_type(4))) float;

__device__ __forceinline__ float lrelu(float x){ return x > 0.f ? x : NEG*x; }
__device__ __forceinline__ unsigned short f2bf(float f){
  unsigned u = __float_as_uint(f);
  u += 0x7fffu + ((u >> 16) & 1u);
  return (unsigned short)(u >> 16);
}
__device__ __forceinline__ float bf2f(unsigned short h){
  return __uint_as_float(((unsigned)h) << 16);
}
// exp without max-subtraction; clamp is overflow guard only (never hit, |l|<=~8 here)
__device__ __forceinline__ float wexp(float l){ return __expf(fminf(l, 30.f)); }

// ---------- merged prep: cast x, transpose W1/W2, build wAb ----------
#define B_CAST ((N_NODES*F_IN/4 + 255)/256)   // 6250
#define B_W1   ((F_IN*C1 + 255)/256)          // 192
#define B_W2   ((C1*C2 + 255)/256)            // 96
#define B_WAB  ((32*F_IN + 255)/256)          // 16
__global__ void prep_kernel(const float* __restrict__ x, const float* __restrict__ W1,
    const float* __restrict__ W2, const float* __restrict__ att_src,
    const float* __restrict__ att_dst, unsigned short* __restrict__ xb,
    unsigned short* __restrict__ w1t, unsigned short* __restrict__ w2t,
    unsigned short* __restrict__ wAb){
  int b = blockIdx.x, tid = threadIdx.x;
  if (b < B_CAST){
    int base = (b*256 + tid)*4;
    if (base >= N_NODES*F_IN) return;
    float4 v = *(const float4*)(x + base);
    ushort4 o; o.x=f2bf(v.x); o.y=f2bf(v.y); o.z=f2bf(v.z); o.w=f2bf(v.w);
    *(ushort4*)(xb + base) = o;
  } else if (b < B_CAST + B_W1){
    int i = (b - B_CAST)*256 + tid;
    if (i >= F_IN*C1) return;
    int n = i / F_IN, k = i % F_IN;
    w1t[i] = f2bf(W1[(size_t)k*C1 + n]);
  } else if (b < B_CAST + B_W1 + B_W2){
    int i = (b - B_CAST - B_W1)*256 + tid;
    if (i >= C1*C2) return;
    int n = i / C1, k = i % C1;
    w2t[i] = f2bf(W2[(size_t)k*C2 + n]);
  } else {
    int i = (b - B_CAST - B_W1 - B_W2)*256 + tid;
    if (i >= 32*F_IN) return;
    int c = i >> 7, k = i & 127;
    float v = 0.f;
    if (c < 12){
      #pragma unroll
      for (int dd=0; dd<D1; ++dd) v += W1[(size_t)k*C1 + c*D1 + dd] * att_src[c*D1 + dd];
    } else if (c < 24){
      int h = c - 12;
      #pragma unroll
      for (int dd=0; dd<D1; ++dd) v += W1[(size_t)k*C1 + h*D1 + dd] * att_dst[h*D1 + dd];
    }
    wAb[i] = f2bf(v);
  }
}

// ---------- bf16 MFMA GEMM (logits): C[M][N] = A[M][K] @ Bt[N][K]^T ----------
template<int BM,int BN,int WM,int WN,bool F32OUT>
__global__ __launch_bounds__(256) void gemm_mfma(const unsigned short* __restrict__ A,
    const unsigned short* __restrict__ Bt, void* __restrict__ Cv,
    int M, int N, int K){
  constexpr int BK = 32;
  __shared__ unsigned short As2[4][BM][8];
  __shared__ unsigned short Bs2[4][BN][8];
  const int tid  = threadIdx.x;
  const int wid  = tid >> 6, lane = tid & 63;
  constexpr int NWX = BN / WN;
  const int wrow = (wid / NWX) * WM, wcol = (wid % NWX) * WN;
  constexpr int MR = WM/16, NR = WN/16;
  const int row0 = blockIdx.x * BM, col0 = blockIdx.y * BN;
  const int r = lane & 15, koct = lane >> 4;
  f32x4 acc[MR][NR];
  #pragma unroll
  for (int m=0;m<MR;m++)
    #pragma unroll
    for (int n=0;n<NR;n++) acc[m][n] = f32x4{0.f,0.f,0.f,0.f};

  for (int k0 = 0; k0 < K; k0 += BK){
    for (int s = tid; s < BM*8; s += 256){
      int rr = s >> 3, cc = (s & 7) * 4;
      int gr = row0 + rr;
      ushort4 v = (gr < M) ? *(const ushort4*)(A + (size_t)gr*K + k0 + cc)
                           : ushort4{0,0,0,0};
      *(ushort4*)(&As2[cc>>3][rr][cc&7]) = v;
    }
    for (int s = tid; s < BN*8; s += 256){
      int rr = s >> 3, cc = (s & 7) * 4;
      ushort4 v = *(const ushort4*)(Bt + (size_t)(col0+rr)*K + k0 + cc);
      *(ushort4*)(&Bs2[cc>>3][rr][cc&7]) = v;
    }
    __syncthreads();
    bf16x8 af[MR], bq[NR];
    #pragma unroll
    for (int m=0;m<MR;m++) af[m] = *(const bf16x8*)(&As2[koct][wrow + m*16 + r][0]);
    #pragma unroll
    for (int n=0;n<NR;n++) bq[n] = *(const bf16x8*)(&Bs2[koct][wcol + n*16 + r][0]);
    #pragma unroll
    for (int m=0;m<MR;m++)
      #pragma unroll
      for (int n=0;n<NR;n++)
        acc[m][n] = __builtin_amdgcn_mfma_f32_16x16x32_bf16(af[m], bq[n], acc[m][n], 0,0,0);
    __syncthreads();
  }
  #pragma unroll
  for (int m=0;m<MR;m++){
    #pragma unroll
    for (int rr=0; rr<4; rr++){
      int grow = row0 + wrow + m*16 + koct*4 + rr;
      if (grow < M){
        #pragma unroll
        for (int n=0;n<NR;n++){
          if constexpr (F32OUT)
            ((float*)Cv)[(size_t)grow*N + col0 + wcol + n*16 + r] = acc[m][n][rr];
          else
            ((unsigned short*)Cv)[(size_t)grow*N + col0 + wcol + n*16 + r] = f2bf(acc[m][n][rr]);
        }
      }
    }
  }
}

// ---------- CSR build ----------
#define EGRID ((ETOT + 255)/256)          // 3321
#define NGRID ((N_NODES + 255)/256)       // 196
__global__ void count_cnt_kernel(const int* __restrict__ ei, const int* __restrict__ batch,
                                 int* __restrict__ counts, int* __restrict__ cnt){
  if ((int)blockIdx.x < EGRID){
    int e = blockIdx.x*256 + threadIdx.x;
    if (e >= ETOT) return;
    int d = (e < N_EDGES) ? ei[N_EDGES + e] : (e - N_EDGES);
    atomicAdd(&counts[d], 1);
  } else {
    int n = (blockIdx.x - EGRID)*256 + threadIdx.x;
    if (n < N_NODES) atomicAdd(&cnt[batch[n]], 1);
  }
}
__global__ __launch_bounds__(SCAN_B) void scan_pass1(const int* __restrict__ counts,
    int* __restrict__ excl, int* __restrict__ bsum){
  __shared__ int sdata[SCAN_B];
  int i = blockIdx.x*SCAN_B + threadIdx.x;
  int v = (i < N_NODES) ? counts[i] : 0;
  sdata[threadIdx.x] = v;
  __syncthreads();
  for (int off=1; off<SCAN_B; off<<=1){
    int t = (threadIdx.x >= off) ? sdata[threadIdx.x-off] : 0;
    __syncthreads();
    sdata[threadIdx.x] += t;
    __syncthreads();
  }
  if (i < N_NODES) excl[i] = sdata[threadIdx.x] - v;
  if (threadIdx.x == SCAN_B-1) bsum[blockIdx.x] = sdata[SCAN_B-1];
}
__global__ void scan_pass3(int* __restrict__ rowptr, const int* __restrict__ bsum,
                           int* __restrict__ cursor){
  __shared__ int carry_s;
  int sblk = blockIdx.x >> 2;
  if (threadIdx.x == 0){
    int c = 0;
    for (int b=0; b<sblk; ++b) c += bsum[b];
    carry_s = c;
  }
  __syncthreads();
  int i = blockIdx.x*256 + (int)threadIdx.x;
  if (i < N_NODES){
    int r = rowptr[i] + carry_s;
    rowptr[i] = r; cursor[i] = r;
  }
  if (i == N_NODES) rowptr[N_NODES] = ETOT;
}
__global__ void scatter_kernel(const int* __restrict__ ei, int* __restrict__ cursor,
                               int* __restrict__ csr_src, int* __restrict__ csr_dst){
  int e = blockIdx.x*blockDim.x + threadIdx.x;
  if (e >= ETOT) return;
  int s, d;
  if (e < N_EDGES){ s = ei[e]; d = ei[N_EDGES + e]; } else { s = d = e - N_EDGES; }
  int slot = atomicAdd(&cursor[d], 1);
  csr_src[slot] = s;
  csr_dst[slot] = d;
}

// ---------- edge-parallel weight precompute: walpha[j][12] = bf16(exp(lrelu(aS+aD))) ----------
__global__ void wprep_kernel(const int* __restrict__ csr, const int* __restrict__ csrd,
                             const float* __restrict__ asd, unsigned short* __restrict__ walpha){
  int j = blockIdx.x*256 + threadIdx.x;
  if (j >= ETOT) return;
  int s = csr[j], d = csrd[j];
  float4 s0 = *(const float4*)(asd + (size_t)s*32);
  float4 s1 = *(const float4*)(asd + (size_t)s*32 + 4);
  float4 s2 = *(const float4*)(asd + (size_t)s*32 + 8);
  float4 d0 = *(const float4*)(asd + (size_t)d*32 + 12);
  float4 d1 = *(const float4*)(asd + (size_t)d*32 + 16);
  float4 d2 = *(const float4*)(asd + (size_t)d*32 + 20);
  float as[12] = {s0.x,s0.y,s0.z,s0.w, s1.x,s1.y,s1.z,s1.w, s2.x,s2.y,s2.z,s2.w};
  float ad[12] = {d0.x,d0.y,d0.z,d0.w, d1.x,d1.y,d1.z,d1.w, d2.x,d2.y,d2.z,d2.w};
  unsigned short wb[12];
  #pragma unroll
  for (int h=0;h<12;h++) wb[h] = f2bf(wexp(lrelu(as[h] + ad[h])));
  unsigned short* wp = walpha + (size_t)j*12;
  *(ushort4*)(wp)   = ushort4{wb[0],wb[1],wb[2],wb[3]};
  *(ushort4*)(wp+4) = ushort4{wb[4],wb[5],wb[6],wb[7]};
  *(ushort4*)(wp+8) = ushort4{wb[8],wb[9],wb[10],wb[11]};
}

// ---------- conv1 grand-fused: 32 lanes/dst, acc[12][4] (occupancy), chunk-32 staged w,
//            x-space agg + W1 MFMA + ReLU + gemm2 partials + a2. out1 never materialized.
// 512 thr = 8 waves = 16 dst/block (2 dst per wave).
__global__ __launch_bounds__(512, 4) void agg1h_kernel(const int* __restrict__ rowptr,
    const int* __restrict__ csr, const unsigned short* __restrict__ xb,
    const unsigned short* __restrict__ walpha, const unsigned short* __restrict__ w1t,
    const unsigned short* __restrict__ w2t, const float* __restrict__ bias1,
    const float* __restrict__ att_src2, const float* __restrict__ att_dst2,
    unsigned short* __restrict__ h2, float* __restrict__ asrc2, float* __restrict__ adst2){
  constexpr int ROWE = 6*F_IN + 8;            // 776 ushorts, per-slot agg row (6 heads)
  constexpr int WROW = 32*12 + 4;             // 388 floats, per-slot weight row (chunk 32)
  constexpr int ROWR = 192 + 8;               // 200 ushorts, relu-out1 half-row
  __shared__ unsigned short agg[16*ROWE];     // 24832 B  (aliased: red at end)
  __shared__ float wlds[16][WROW];            // 24832 B  (aliased: reluLDS in epilogue)

  unsigned short* reluLDS = (unsigned short*)&wlds[0][0];   // 16 x ROWR ushorts = 6400 B
  float* red = (float*)&agg[0];                              // a2 reduce scratch

  const int tid  = threadIdx.x;
  const int wv   = tid >> 6;                  // wave 0..7
  const int lane = tid & 63;
  const int half = lane >> 5;                 // which dst of the wave's pair
  const int t32  = lane & 31;                 // lane within dst (4 feats each)
  const int base = lane & 32;                 // wave-lane base of this 32-lane group
  const int slot = wv*2 + half;               // 0..15 dst in block
  const int d    = blockIdx.x*16 + slot;
  const int r0 = rowptr[d], r1 = rowptr[d+1];

  float acc[12][4];
  #pragma unroll
  for (int h=0;h<12;h++)
    #pragma unroll
    for (int i=0;i<4;i++) acc[h][i] = 0.f;
  float ss[12];
  #pragma unroll
  for (int h=0;h<12;h++) ss[h] = 0.f;

  // ---- main loop: 32-edge chunks; all 32 lanes stage (csr reg + w -> LDS) ----
  for (int c0 = r0; c0 < r1; c0 += 32){
    int nc = min(32, r1 - c0);
    int s_st = 0;
    if (t32 < nc){
      int j = c0 + t32;
      s_st = csr[j];
      const unsigned short* wp = walpha + (size_t)j*12;
      ushort4 u0 = *(const ushort4*)(wp);
      ushort4 u1 = *(const ushort4*)(wp+4);
      ushort4 u2 = *(const ushort4*)(wp+8);
      float w[12] = {bf2f(u0.x),bf2f(u0.y),bf2f(u0.z),bf2f(u0.w),
                     bf2f(u1.x),bf2f(u1.y),bf2f(u1.z),bf2f(u1.w),
                     bf2f(u2.x),bf2f(u2.y),bf2f(u2.z),bf2f(u2.w)};
      #pragma unroll
      for (int h=0;h<12;h++) ss[h] += w[h];
      *(float4*)(&wlds[slot][t32*12 + 0]) = float4{w[0],w[1],w[2],w[3]};
      *(float4*)(&wlds[slot][t32*12 + 4]) = float4{w[4],w[5],w[6],w[7]};
      *(float4*)(&wlds[slot][t32*12 + 8]) = float4{w[8],w[9],w[10],w[11]};
    }
    __builtin_amdgcn_wave_barrier();
    // 3-deep x prefetch (ushort4 per lane; 32 lanes cover the 256B row)
    int sA = __shfl(s_st, base + 0);
    ushort4 xA = *(const ushort4*)(xb + (size_t)sA*F_IN + t32*4);
    ushort4 xB = {0,0,0,0}, xC = {0,0,0,0};
    if (nc > 1){
      int sB = __shfl(s_st, base + 1);
      xB = *(const ushort4*)(xb + (size_t)sB*F_IN + t32*4);
    }
    if (nc > 2){
      int sC = __shfl(s_st, base + 2);
      xC = *(const ushort4*)(xb + (size_t)sC*F_IN + t32*4);
    }
    for (int e = 0; e < nc; ++e){
      ushort4 cx = xA;
      xA = xB; xB = xC;
      if (e + 3 < nc){
        int sN = __shfl(s_st, base + e + 3);
        xC = *(const ushort4*)(xb + (size_t)sN*F_IN + t32*4);
      }
      float4 w0 = *(const float4*)(&wlds[slot][e*12 + 0]);
      float4 w1 = *(const float4*)(&wlds[slot][e*12 + 4]);
      float4 w2 = *(const float4*)(&wlds[slot][e*12 + 8]);
      float xf[4] = {bf2f(cx.x), bf2f(cx.y), bf2f(cx.z), bf2f(cx.w)};
      float w[12] = {w0.x,w0.y,w0.z,w0.w, w1.x,w1.y,w1.z,w1.w, w2.x,w2.y,w2.z,w2.w};
      #pragma unroll
      for (int h=0;h<12;h++)
        #pragma unroll
        for (int i=0;i<4;i++) acc[h][i] += w[h]*xf[i];
    }
    __builtin_amdgcn_wave_barrier();
  }

  // reduce ss over 32-lane group; normalize factors
  #pragma unroll
  for (int h=0;h<12;h++){
    #pragma unroll
    for (int off=16; off; off>>=1) ss[h] += __shfl_xor(ss[h], off);
  }
  float inv[12];
  #pragma unroll
  for (int h=0;h<12;h++) inv[h] = 1.f / ss[h];

  // ---- epilogue: per 6-head half: agg->LDS, W1-MFMA + bias + ReLU -> reluLDS,
  //      then partial gemm2 (K=192) accumulating h2 in regs ----
  const int er = lane & 15, eq = lane >> 4;
  f32x4 h2acc = {0.f,0.f,0.f,0.f};
  #pragma unroll
  for (int hf = 0; hf < 2; ++hf){
    __syncthreads();   // main loop done (hf=0) / prev half's reluLDS+agg reads done (hf=1)
    #pragma unroll
    for (int h = 0; h < 6; ++h){
      int hh = hf*6 + h;
      ushort4 v;
      v.x = f2bf(acc[hh][0]*inv[hh]); v.y = f2bf(acc[hh][1]*inv[hh]);
      v.z = f2bf(acc[hh][2]*inv[hh]); v.w = f2bf(acc[hh][3]*inv[hh]);
      *(ushort4*)(&agg[slot*ROWE + h*F_IN + t32*4]) = v;
    }
    __syncthreads();
    // W1 transform: 12 tiles (192 cols this half) over 8 waves
    for (int tt = wv; tt < 12; tt += 8){
      int h = tt >> 1, nb = tt & 1;
      int hh = hf*6 + h;
      f32x4 c = {0.f,0.f,0.f,0.f};
      #pragma unroll
      for (int kk=0; kk<4; ++kk){
        bf16x8 af = *(const bf16x8*)(&agg[er*ROWE + h*F_IN + kk*32 + eq*8]);
        bf16x8 bq = *(const bf16x8*)(w1t + (size_t)(hh*32 + nb*16 + er)*F_IN + kk*32 + eq*8);
        c = __builtin_amdgcn_mfma_f32_16x16x32_bf16(af, bq, c, 0,0,0);
      }
      int lcol = tt*16 + er;                    // local col within half (0..191)
      float bv = bias1[hf*192 + lcol];
      #pragma unroll
      for (int rr=0; rr<4; ++rr){
        int row = eq*4 + rr;                    // dst row 0..15
        reluLDS[row*ROWR + lcol] = f2bf(fmaxf(c[rr] + bv, 0.f));
      }
    }
    __syncthreads();
    // partial gemm2: waves 0..3 own h2 cols [wv*16, wv*16+16), K=192 this half
    if (wv < 4){
      #pragma unroll
      for (int kk=0; kk<6; ++kk){
        bf16x8 af = *(const bf16x8*)(&reluLDS[er*ROWR + kk*32 + eq*8]);
        bf16x8 bq = *(const bf16x8*)(w2t + (size_t)(wv*16 + er)*C1 + hf*192 + kk*32 + eq*8);
        h2acc = __builtin_amdgcn_mfma_f32_16x16x32_bf16(af, bq, h2acc, 0,0,0);
      }
    }
  }
  __syncthreads();   // reluLDS/agg reads done; agg region reusable as red

  // ---- write h2 (bf16) + a2 dots (waves 0..3) ----
  if (wv < 4){
    float attS = att_src2[wv*16 + er];
    float attD = att_dst2[wv*16 + er];
    float psum[4], pdum[4];
    #pragma unroll
    for (int rr=0; rr<4; ++rr){
      int row = eq*4 + rr;
      int gn = blockIdx.x*16 + row;
      h2[(size_t)gn*C2 + wv*16 + er] = f2bf(h2acc[rr]);
      psum[rr] = h2acc[rr]*attS;
      pdum[rr] = h2acc[rr]*attD;
    }
    #pragma unroll
    for (int rr=0; rr<4; ++rr){
      #pragma unroll
      for (int off=8; off; off>>=1){
        psum[rr] += __shfl_xor(psum[rr], off);
        pdum[rr] += __shfl_xor(pdum[rr], off);
      }
    }
    if (er == 0){
      #pragma unroll
      for (int rr=0; rr<4; ++rr){
        int row = eq*4 + rr;
        red[(wv*16 + row)*2 + 0] = psum[rr];
        red[(wv*16 + row)*2 + 1] = pdum[rr];
      }
    }
  }
  __syncthreads();
  if (tid < 32){
    int row = tid >> 1, which = tid & 1;
    float v = red[row*2+which] + red[(16+row)*2+which] + red[(32+row)*2+which] + red[(48+row)*2+which];
    int gn = blockIdx.x*16 + row;
    if (which == 0) asrc2[gn] = v; else adst2[gn] = v;
  }
}

// ---------- conv2: no-max softmax + aggregation + pool atomics ----------
__global__ __launch_bounds__(256) void agg2s_kernel(const int* __restrict__ rowptr,
    const int* __restrict__ csr, const unsigned short* __restrict__ h2,
    const float* __restrict__ asrc, const float* __restrict__ adst,
    const float* __restrict__ bias, const int* __restrict__ batch,
    float* __restrict__ pool){
  const int tid  = threadIdx.x;
  const int slot = tid >> 4;
  const int t16  = tid & 15;
  const int base = ((tid & 63) >> 4) * 16;
  const int d    = blockIdx.x*16 + slot;
  const int r0 = rowptr[d], r1 = rowptr[d+1];
  const float ad = adst[d];

  float ssp = 0.f;
  float a0=0.f, a1=0.f, a2=0.f, a3=0.f;

  for (int c0 = r0; c0 < r1; c0 += 16){
    int nc = min(16, r1 - c0);
    int s_st = 0; float w_st = 0.f;
    if (t16 < nc){
      s_st = csr[c0 + t16];
      w_st = wexp(lrelu(asrc[s_st] + ad));
      ssp += w_st;
    }
    int sA = __shfl(s_st, base + 0);
    ushort4 xA = *(const ushort4*)(h2 + (size_t)sA*C2 + t16*4);
    ushort4 xB = {0,0,0,0}, xC = {0,0,0,0};
    if (nc > 1){
      int sB = __shfl(s_st, base + 1);
      xB = *(const ushort4*)(h2 + (size_t)sB*C2 + t16*4);
    }
    if (nc > 2){
      int sC = __shfl(s_st, base + 2);
      xC = *(const ushort4*)(h2 + (size_t)sC*C2 + t16*4);
    }
    for (int e = 0; e < nc; ++e){
      ushort4 cx = xA;
      xA = xB; xB = xC;
      if (e + 3 < nc){
        int sN = __shfl(s_st, base + e + 3);
        xC = *(const ushort4*)(h2 + (size_t)sN*C2 + t16*4);
      }
      float w = __shfl(w_st, base + e);
      a0 += w*bf2f(cx.x);
      a1 += w*bf2f(cx.y);
      a2 += w*bf2f(cx.z);
      a3 += w*bf2f(cx.w);
    }
  }
  #pragma unroll
  for (int off=8; off; off>>=1) ssp += __shfl_xor(ssp, off);
  float inv = 1.f / ssp;
  int g = batch[d];
  int fb = t16*4;
  atomicAdd(&pool[g*C2 + fb+0], a0*inv + bias[fb+0]);
  atomicAdd(&pool[g*C2 + fb+1], a1*inv + bias[fb+1]);
  atomicAdd(&pool[g*C2 + fb+2], a2*inv + bias[fb+2]);
  atomicAdd(&pool[g*C2 + fb+3], a3*inv + bias[fb+3]);
}

__global__ void finalize_kernel(const float* __restrict__ sums, const int* __restrict__ cnt,
                                float* __restrict__ out){
  int i = blockIdx.x*blockDim.x + threadIdx.x;
  if (i >= G_GRAPHS*C2) return;
  int g = i >> 6;
  out[i] = sums[i] / fmaxf((float)cnt[g], 1.f);
}

// ---------- launch ----------
extern "C" void kernel_launch(void* const* d_in, const int* in_sizes, int n_in,
                              void* d_out, int out_size, void* d_ws, size_t ws_size,
                              hipStream_t stream) {
  const float* x        = (const float*)d_in[0];
  const int*   ei       = (const int*)  d_in[1];
  const int*   batch    = (const int*)  d_in[2];
  const float* W1       = (const float*)d_in[3];
  const float* att_src1 = (const float*)d_in[4];
  const float* att_dst1 = (const float*)d_in[5];
  const float* bias1    = (const float*)d_in[6];
  const float* W2       = (const float*)d_in[7];
  const float* att_src2 = (const float*)d_in[8];
  const float* att_dst2 = (const float*)d_in[9];
  const float* bias2    = (const float*)d_in[10];
  float* out = (float*)d_out;

  char* ws = (char*)d_ws;
  size_t o = 0;
  auto alloc = [&](size_t bytes)->size_t{ size_t r=o; o=(o+bytes+255)&~(size_t)255; return r; };

  size_t xb_o     = alloc((size_t)N_NODES*F_IN*2);   // 12.8 MB
  size_t w1t_o    = alloc((size_t)C1*F_IN*2);
  size_t w2t_o    = alloc((size_t)C2*C1*2);
  size_t wab_o    = alloc((size_t)32*F_IN*2);
  size_t asd_o    = alloc((size_t)N_NODES*32*4);     // 6.4 MB (src:0-11, dst:12-23)
  size_t h2_o     = alloc((size_t)N_NODES*C2*2);     // 6.4 MB
  size_t asrc2_o  = alloc((size_t)N_NODES*4);
  size_t adst2_o  = alloc((size_t)N_NODES*4);
  size_t walpha_o = alloc((size_t)ETOT*12*2);        // 20.4 MB bf16 unnormalized w
  size_t zero_beg = o;
  size_t counts_o = alloc((size_t)N_NODES*4);
  size_t pool_o   = alloc((size_t)G_GRAPHS*C2*4);
  size_t cnt_o    = alloc((size_t)G_GRAPHS*4);
  size_t zero_end = o;
  size_t rowptr_o = alloc((size_t)(N_NODES+1)*4);
  size_t bsum_o   = alloc((size_t)NBLK_SCAN*4);
  size_t cursor_o = alloc((size_t)N_NODES*4);
  size_t csr_o    = alloc((size_t)ETOT*4);
  size_t csrd_o   = alloc((size_t)ETOT*4);

  unsigned short* xb    = (unsigned short*)(ws + xb_o);
  unsigned short* w1t   = (unsigned short*)(ws + w1t_o);
  unsigned short* w2t   = (unsigned short*)(ws + w2t_o);
  unsigned short* wab   = (unsigned short*)(ws + wab_o);
  float* asd    = (float*)(ws + asd_o);
  unsigned short* h2b   = (unsigned short*)(ws + h2_o);
  float* asrc2  = (float*)(ws + asrc2_o);
  float* adst2  = (float*)(ws + adst2_o);
  unsigned short* walpha = (unsigned short*)(ws + walpha_o);
  int*   counts = (int*)  (ws + counts_o);
  float* poolf  = (float*)(ws + pool_o);
  int*   cnt    = (int*)  (ws + cnt_o);
  int*   rowptr = (int*)  (ws + rowptr_o);
  int*   bsum   = (int*)  (ws + bsum_o);
  int*   cursor = (int*)  (ws + cursor_o);
  int*   csrsrc = (int*)  (ws + csr_o);
  int*   csrdst = (int*)  (ws + csrd_o);

  hipMemsetAsync(ws + zero_beg, 0, zero_end - zero_beg, stream);

  const int TPB = 256;

  // prep
  prep_kernel<<<B_CAST + B_W1 + B_W2 + B_WAB, TPB, 0, stream>>>(
      x, W1, W2, att_src1, att_dst1, xb, w1t, w2t, wab);

  // CSR build
  count_cnt_kernel<<<EGRID + NGRID, TPB, 0, stream>>>(ei, batch, counts, cnt);
  scan_pass1<<<NBLK_SCAN, SCAN_B, 0, stream>>>(counts, rowptr, bsum);
  scan_pass3<<<(N_NODES + 1 + 255)/256, TPB, 0, stream>>>(rowptr, bsum, cursor);
  scatter_kernel<<<EGRID, TPB, 0, stream>>>(ei, cursor, csrsrc, csrdst);

  // conv1 logits
  gemm_mfma<64,32,32,16,true><<<dim3((N_NODES+63)/64, 1), 256, 0, stream>>>(xb, wab, asd, N_NODES, 32, F_IN);
  // per-edge weights (bf16, unnormalized, no-max)
  wprep_kernel<<<EGRID, TPB, 0, stream>>>(csrsrc, csrdst, asd, walpha);
  // conv1 agg + W1 + gemm2 + a2 grand fusion (32 lanes/dst)
  agg1h_kernel<<<N_NODES/16, 512, 0, stream>>>(rowptr, csrsrc, xb, walpha, w1t, w2t,
                                               bias1, att_src2, att_dst2, h2b, asrc2, adst2);
  // conv2 aggregation + pool
  agg2s_kernel<<<(N_NODES+15)/16, TPB, 0, stream>>>(rowptr, csrsrc, h2b, asrc2, adst2, bias2, batch, poolf);

  // pool finalize
  finalize_kernel<<<(G_GRAPHS*C2 + TPB-1)/TPB, TPB, 0, stream>>>(poolf, cnt, out);
}